// Round 1
// baseline (239.032 us; speedup 1.0000x reference)
//
#include <hip/hip_runtime.h>
#include <cstdint>
#include <cstddef>

// Problem dims (fixed by the reference setup_inputs):
#define B_DIM   8192
#define IN_DIM  1024
#define OUT_DIM 4096

typedef __attribute__((ext_vector_type(8))) short s16x8;   // 8 bf16 (4 VGPRs) MFMA frag
typedef __attribute__((ext_vector_type(4))) float f32x4;   // MFMA accumulator

// fp32 -> bf16 (RNE)
__device__ __forceinline__ unsigned short f32_to_bf16(float f) {
    unsigned int u = __float_as_uint(f);
    u += 0x7FFFu + ((u >> 16) & 1u);
    return (unsigned short)(u >> 16);
}

// async global->LDS DMA, 16B per lane. LDS dest is wave-uniform base + lane*16.
__device__ __forceinline__ void async_copy16(const void* gptr, void* ldsptr) {
    __builtin_amdgcn_global_load_lds(
        (__attribute__((address_space(1))) void*)gptr,
        (__attribute__((address_space(3))) void*)ldsptr,
        16, 0, 0);
}

// ---------------------------------------------------------------------------
// Kernel 1: x (fp32, row-major B x IN) -> bf16 copy + per-row sum of squares.
// One block per row; 256 threads * float4 = 1024 elements.
// ---------------------------------------------------------------------------
__global__ __launch_bounds__(256) void convert_x_kernel(
    const float* __restrict__ x, unsigned short* __restrict__ xb,
    float* __restrict__ xsq)
{
    const int b = blockIdx.x;
    const int t = threadIdx.x;
    float4 v = ((const float4*)x)[(size_t)b * 256 + t];
    ushort4 h;
    h.x = f32_to_bf16(v.x);
    h.y = f32_to_bf16(v.y);
    h.z = f32_to_bf16(v.z);
    h.w = f32_to_bf16(v.w);
    ((ushort4*)xb)[(size_t)b * 256 + t] = h;

    float s = v.x * v.x + v.y * v.y + v.z * v.z + v.w * v.w;
    #pragma unroll
    for (int off = 32; off > 0; off >>= 1) s += __shfl_down(s, off, 64);
    __shared__ float red[4];
    if ((t & 63) == 0) red[t >> 6] = s;
    __syncthreads();
    if (t == 0) xsq[b] = red[0] + red[1] + red[2] + red[3];
}

// ---------------------------------------------------------------------------
// Kernel 2: W (fp32, IN x OUT row-major) -> wT (bf16, OUT x IN row-major)
// via 64x64 LDS-tiled transpose; fused column sum-of-squares into wsq (atomic).
// grid: (OUT/64, IN/64), 256 threads.
// ---------------------------------------------------------------------------
__global__ __launch_bounds__(256) void convert_w_kernel(
    const float* __restrict__ w, unsigned short* __restrict__ wT,
    float* __restrict__ wsq)
{
    __shared__ float tile[64][65];   // +1 pad: conflict-free column reads
    const int t  = threadIdx.x;
    const int o0 = blockIdx.x * 64;
    const int i0 = blockIdx.y * 64;

    // coalesced read: thread covers 4 consecutive o, 4 strided i
    const int oc = (t & 15) * 4;
    const int ir = t >> 4;
    #pragma unroll
    for (int r = 0; r < 4; ++r) {
        const int i = ir + r * 16;
        float4 v = *(const float4*)(w + (size_t)(i0 + i) * OUT_DIM + o0 + oc);
        tile[i][oc + 0] = v.x;
        tile[i][oc + 1] = v.y;
        tile[i][oc + 2] = v.z;
        tile[i][oc + 3] = v.w;
    }
    __syncthreads();

    // write transposed: thread owns one o-row, 16 consecutive i (32B store)
    const int ol = t >> 2;
    const int c  = t & 3;
    float s = 0.0f;
    s16x8 p0, p1;
    #pragma unroll
    for (int j = 0; j < 8; ++j) {
        float f0 = tile[c * 16 + j][ol];
        float f1 = tile[c * 16 + 8 + j][ol];
        s += f0 * f0 + f1 * f1;
        p0[j] = (short)f32_to_bf16(f0);
        p1[j] = (short)f32_to_bf16(f1);
    }
    s16x8* dst = (s16x8*)(wT + (size_t)(o0 + ol) * IN_DIM + i0 + c * 16);
    dst[0] = p0;
    dst[1] = p1;

    // reduce sum-of-squares over the 4 chunk-threads of this o (adjacent lanes)
    s += __shfl_xor(s, 1, 64);
    s += __shfl_xor(s, 2, 64);
    if (c == 0) atomicAdd(&wsq[o0 + ol], s);
}

// ---------------------------------------------------------------------------
// Kernel 3: GEMM  cross = xb @ wT^T  (A: B_DIM x IN, Bt: OUT x IN, both bf16
// row-major) with fused epilogue  out = xsq[m] + wsq[n] - 2*cross.
// 128x128 tile, BK=64, 256 threads = 4 waves, each wave 64x64 via 4x4 frags
// of mfma_f32_16x16x32_bf16. global_load_lds width-16 staging with XOR slot
// swizzle (DMA needs lane-contiguous LDS; swizzle makes frag reads
// conflict-free: rows 0..7 hit all 32 banks, rows 8..15 are a free 2-way).
// ---------------------------------------------------------------------------
__global__ __launch_bounds__(256) void rbf_gemm_kernel(
    const unsigned short* __restrict__ A,    // xb  [B_DIM][IN_DIM]
    const unsigned short* __restrict__ Bt,   // wT  [OUT_DIM][IN_DIM]
    const float* __restrict__ xsq,
    const float* __restrict__ wsq,
    float* __restrict__ out)
{
    __shared__ __align__(16) unsigned short As[128 * 64];
    __shared__ __align__(16) unsigned short Bs[128 * 64];

    const int t    = threadIdx.x;
    const int w    = t >> 6;     // wave 0..3
    const int l    = t & 63;
    const int quad = l >> 4;     // lane group 0..3
    const int l16  = l & 15;
    const int tile_m  = blockIdx.x * 128;
    const int tile_n  = blockIdx.y * 128;
    const int waveRow = w >> 1;  // 0..1
    const int waveCol = w & 1;   // 0..1

    f32x4 acc[4][4];
    #pragma unroll
    for (int mi = 0; mi < 4; ++mi)
        #pragma unroll
        for (int ni = 0; ni < 4; ++ni)
            acc[mi][ni] = (f32x4){0.f, 0.f, 0.f, 0.f};

    for (int kt = 0; kt < IN_DIM / 64; ++kt) {
        const int k0 = kt * 64;
        // Stage A,B tiles: 128 rows x 64 k (16 KB each). 1024 16B-slots per
        // tile; slot s=(row<<3)|kb_lds holds global k-block kb_lds ^ (row&7).
        #pragma unroll
        for (int it = 0; it < 4; ++it) {
            const int s   = it * 256 + t;        // == wave base + lane
            const int row = s >> 3;
            const int kb  = (s & 7) ^ (row & 7); // swizzled global k-block
            const int ldsbase = (it * 256 + w * 64) * 8;  // wave-uniform, ushorts
            async_copy16(A  + (size_t)(tile_m + row) * IN_DIM + k0 + kb * 8,
                         As + ldsbase);
            async_copy16(Bt + (size_t)(tile_n + row) * IN_DIM + k0 + kb * 8,
                         Bs + ldsbase);
        }
        __syncthreads();   // drains vmcnt for the DMA

        #pragma unroll
        for (int ks = 0; ks < 2; ++ks) {
            s16x8 af[4], bfr[4];
            #pragma unroll
            for (int mi = 0; mi < 4; ++mi) {
                const int row = waveRow * 64 + mi * 16 + l16;     // A: m = lane&15
                const int kb  = (ks * 4 + quad) ^ (row & 7);      // k = quad*8+j
                af[mi] = *(const s16x8*)(As + row * 64 + kb * 8);
            }
            #pragma unroll
            for (int ni = 0; ni < 4; ++ni) {
                const int row = waveCol * 64 + ni * 16 + l16;     // B: n = lane&15
                const int kb  = (ks * 4 + quad) ^ (row & 7);
                bfr[ni] = *(const s16x8*)(Bs + row * 64 + kb * 8);
            }
            #pragma unroll
            for (int mi = 0; mi < 4; ++mi)
                #pragma unroll
                for (int ni = 0; ni < 4; ++ni)
                    acc[mi][ni] = __builtin_amdgcn_mfma_f32_16x16x32_bf16(
                        af[mi], bfr[ni], acc[mi][ni], 0, 0, 0);
        }
        __syncthreads();
    }

    // Epilogue. C/D layout: col(n)=lane&15, row(m)=quad*4+reg.
    const int m0 = tile_m + waveRow * 64 + quad * 4;
    const int n0 = tile_n + waveCol * 64 + l16;
    #pragma unroll
    for (int mi = 0; mi < 4; ++mi) {
        #pragma unroll
        for (int r = 0; r < 4; ++r) {
            const int m  = m0 + mi * 16 + r;
            const float xs = xsq[m];
            #pragma unroll
            for (int ni = 0; ni < 4; ++ni) {
                const int n = n0 + ni * 16;
                out[(size_t)m * OUT_DIM + n] = xs + wsq[n] - 2.0f * acc[mi][ni][r];
            }
        }
    }
}

// ---------------------------------------------------------------------------
extern "C" void kernel_launch(void* const* d_in, const int* in_sizes, int n_in,
                              void* d_out, int out_size, void* d_ws, size_t ws_size,
                              hipStream_t stream)
{
    const float* x   = (const float*)d_in[0];   // (8192, 1024) fp32
    const float* wgt = (const float*)d_in[1];   // (1024, 4096) fp32
    float* out = (float*)d_out;                 // (8192, 4096) fp32
    char*  ws  = (char*)d_ws;

    // workspace layout: xb (16 MB) | wT (8 MB) | xsq (32 KB) | wsq (16 KB)
    unsigned short* xb = (unsigned short*)ws;
    unsigned short* wT = (unsigned short*)(ws + (size_t)B_DIM * IN_DIM * 2);
    float* xsq = (float*)(ws + (size_t)B_DIM * IN_DIM * 2 + (size_t)OUT_DIM * IN_DIM * 2);
    float* wsq = xsq + B_DIM;

    hipMemsetAsync(wsq, 0, OUT_DIM * sizeof(float), stream);
    convert_x_kernel<<<B_DIM, 256, 0, stream>>>(x, xb, xsq);
    convert_w_kernel<<<dim3(OUT_DIM / 64, IN_DIM / 64), 256, 0, stream>>>(wgt, wT, wsq);
    rbf_gemm_kernel<<<dim3(B_DIM / 128, OUT_DIM / 128), 256, 0, stream>>>(xb, wT, xsq, wsq, out);
}

// Round 2
// 233.575 us; speedup vs baseline: 1.0234x; 1.0234x over previous
//
#include <hip/hip_runtime.h>
#include <cstdint>
#include <cstddef>

// Problem dims (fixed by the reference setup_inputs):
#define B_DIM   8192
#define IN_DIM  1024
#define OUT_DIM 4096

typedef __attribute__((ext_vector_type(8)))  short s16x8;   // 8 bf16 (4 VGPRs) MFMA frag
typedef __attribute__((ext_vector_type(16))) float f32x16;  // 32x32 MFMA accumulator

// fp32 -> bf16 (RNE)
__device__ __forceinline__ unsigned short f32_to_bf16(float f) {
    unsigned int u = __float_as_uint(f);
    u += 0x7FFFu + ((u >> 16) & 1u);
    return (unsigned short)(u >> 16);
}

// async global->LDS DMA, 16B per lane. LDS dest is wave-uniform base + lane*16.
__device__ __forceinline__ void async_copy16(const void* gptr, void* ldsptr) {
    __builtin_amdgcn_global_load_lds(
        (__attribute__((address_space(1))) void*)gptr,
        (__attribute__((address_space(3))) void*)ldsptr,
        16, 0, 0);
}

// ---------------------------------------------------------------------------
// Kernel 1: x (fp32, B x IN row-major) -> bf16 copy + per-row sum of squares.
// 4 rows per block (one row per wave); 4 float4 per lane; wave-shuffle-only
// reduction (no LDS, no barriers). Blocks 0..15 also zero wsq (runs before
// convert_w's atomics by stream order) so no separate memset dispatch.
// ---------------------------------------------------------------------------
__global__ __launch_bounds__(256) void convert_x_kernel(
    const float* __restrict__ x, unsigned short* __restrict__ xb,
    float* __restrict__ xsq, float* __restrict__ wsq)
{
    const int t  = threadIdx.x;
    const int wv = t >> 6;
    const int l  = t & 63;
    const int b  = blockIdx.x * 4 + wv;

    const float4* src = (const float4*)(x  + (size_t)b * IN_DIM);
    ushort4*      dst = (ushort4*)     (xb + (size_t)b * IN_DIM);

    float s = 0.0f;
    #pragma unroll
    for (int j = 0; j < 4; ++j) {
        float4 v = src[l + 64 * j];
        ushort4 h;
        h.x = f32_to_bf16(v.x);
        h.y = f32_to_bf16(v.y);
        h.z = f32_to_bf16(v.z);
        h.w = f32_to_bf16(v.w);
        dst[l + 64 * j] = h;
        s += v.x * v.x + v.y * v.y + v.z * v.z + v.w * v.w;
    }
    #pragma unroll
    for (int off = 32; off > 0; off >>= 1) s += __shfl_down(s, off, 64);
    if (l == 0) xsq[b] = s;

    if (blockIdx.x < OUT_DIM / 256) wsq[blockIdx.x * 256 + t] = 0.0f;
}

// ---------------------------------------------------------------------------
// Kernel 2: W (fp32, IN x OUT row-major) -> wT (bf16, OUT x IN row-major)
// via 64x64 LDS-tiled transpose; fused column sum-of-squares into wsq (atomic).
// grid: (OUT/64, IN/64), 256 threads.
// ---------------------------------------------------------------------------
__global__ __launch_bounds__(256) void convert_w_kernel(
    const float* __restrict__ w, unsigned short* __restrict__ wT,
    float* __restrict__ wsq)
{
    __shared__ float tile[64][65];   // +1 pad: conflict-free column reads
    const int t  = threadIdx.x;
    const int o0 = blockIdx.x * 64;
    const int i0 = blockIdx.y * 64;

    // coalesced read: thread covers 4 consecutive o, 4 strided i
    const int oc = (t & 15) * 4;
    const int ir = t >> 4;
    #pragma unroll
    for (int r = 0; r < 4; ++r) {
        const int i = ir + r * 16;
        float4 v = *(const float4*)(w + (size_t)(i0 + i) * OUT_DIM + o0 + oc);
        tile[i][oc + 0] = v.x;
        tile[i][oc + 1] = v.y;
        tile[i][oc + 2] = v.z;
        tile[i][oc + 3] = v.w;
    }
    __syncthreads();

    // write transposed: thread owns one o-row, 16 consecutive i (32B store)
    const int ol = t >> 2;
    const int c  = t & 3;
    float s = 0.0f;
    s16x8 p0, p1;
    #pragma unroll
    for (int j = 0; j < 8; ++j) {
        float f0 = tile[c * 16 + j][ol];
        float f1 = tile[c * 16 + 8 + j][ol];
        s += f0 * f0 + f1 * f1;
        p0[j] = (short)f32_to_bf16(f0);
        p1[j] = (short)f32_to_bf16(f1);
    }
    s16x8* dstp = (s16x8*)(wT + (size_t)(o0 + ol) * IN_DIM + i0 + c * 16);
    dstp[0] = p0;
    dstp[1] = p1;

    // reduce sum-of-squares over the 4 chunk-threads of this o (adjacent lanes)
    s += __shfl_xor(s, 1, 64);
    s += __shfl_xor(s, 2, 64);
    if (c == 0) atomicAdd(&wsq[o0 + ol], s);
}

// ---------------------------------------------------------------------------
// Kernel 3: GEMM  cross = xb @ wT^T  (A: B_DIM x IN, Bt: OUT x IN, both bf16
// row-major) with fused epilogue  out = xsq[m] + wsq[n] - 2*cross.
// 128x128 tile, BK=64, 256 threads = 4 waves, each wave 64x64 via 2x2 frags
// of mfma_f32_32x32x16_bf16 (2495 TF ceiling vs 2176 for 16x16 — m119).
// global_load_lds width-16 staging with XOR slot swizzle (DMA needs
// lane-contiguous LDS; swizzle keeps frag reads at the conflict-free floor;
// measured SQ_LDS_BANK_CONFLICT = 0 in round 1).
// ---------------------------------------------------------------------------
__global__ __launch_bounds__(256) void rbf_gemm_kernel(
    const unsigned short* __restrict__ A,    // xb  [B_DIM][IN_DIM]
    const unsigned short* __restrict__ Bt,   // wT  [OUT_DIM][IN_DIM]
    const float* __restrict__ xsq,
    const float* __restrict__ wsq,
    float* __restrict__ out)
{
    __shared__ __align__(16) unsigned short As[128 * 64];
    __shared__ __align__(16) unsigned short Bs[128 * 64];

    const int t    = threadIdx.x;
    const int w    = t >> 6;     // wave 0..3
    const int l    = t & 63;
    const int l32  = l & 31;
    const int half = l >> 5;     // 0..1
    const int tile_m  = blockIdx.x * 128;
    const int tile_n  = blockIdx.y * 128;
    const int waveRow = w >> 1;  // 0..1
    const int waveCol = w & 1;   // 0..1

    f32x16 acc[2][2];
    #pragma unroll
    for (int mi = 0; mi < 2; ++mi)
        #pragma unroll
        for (int ni = 0; ni < 2; ++ni)
            #pragma unroll
            for (int r = 0; r < 16; ++r)
                acc[mi][ni][r] = 0.0f;

    for (int kt = 0; kt < IN_DIM / 64; ++kt) {
        const int k0 = kt * 64;
        // Stage A,B tiles: 128 rows x 64 k (16 KB each). 1024 16B-slots per
        // tile; slot s=(row<<3)|kb_lds holds global k-block kb_lds ^ (row&7).
        #pragma unroll
        for (int it = 0; it < 4; ++it) {
            const int s   = it * 256 + t;        // == wave base + lane
            const int row = s >> 3;
            const int kb  = (s & 7) ^ (row & 7); // swizzled global k-block
            const int ldsbase = (it * 256 + w * 64) * 8;  // wave-uniform, ushorts
            async_copy16(A  + (size_t)(tile_m + row) * IN_DIM + k0 + kb * 8,
                         As + ldsbase);
            async_copy16(Bt + (size_t)(tile_n + row) * IN_DIM + k0 + kb * 8,
                         Bs + ldsbase);
        }
        __syncthreads();   // drains vmcnt for the DMA

        // 4 ksteps of K=16. A frag: lane holds A[m=l&31][k=(l>>5)*8+j]+ks*16.
        #pragma unroll
        for (int ks = 0; ks < 4; ++ks) {
            const int kb = ks * 2 + half;        // 16B k-block index
            s16x8 af[2], bfr[2];
            #pragma unroll
            for (int mi = 0; mi < 2; ++mi) {
                const int row = waveRow * 64 + mi * 32 + l32;
                af[mi] = *(const s16x8*)(As + row * 64 + (kb ^ (row & 7)) * 8);
            }
            #pragma unroll
            for (int ni = 0; ni < 2; ++ni) {
                const int row = waveCol * 64 + ni * 32 + l32;
                bfr[ni] = *(const s16x8*)(Bs + row * 64 + (kb ^ (row & 7)) * 8);
            }
            #pragma unroll
            for (int mi = 0; mi < 2; ++mi)
                #pragma unroll
                for (int ni = 0; ni < 2; ++ni)
                    acc[mi][ni] = __builtin_amdgcn_mfma_f32_32x32x16_bf16(
                        af[mi], bfr[ni], acc[mi][ni], 0, 0, 0);
        }
        __syncthreads();
    }

    // Epilogue. 32x32 C/D layout: col(n)=lane&31, row(m)=(r&3)+8*(r>>2)+4*(l>>5).
    #pragma unroll
    for (int mi = 0; mi < 2; ++mi) {
        const int mbase = tile_m + waveRow * 64 + mi * 32 + 4 * half;
        #pragma unroll
        for (int r2 = 0; r2 < 4; ++r2) {
            #pragma unroll
            for (int r1 = 0; r1 < 4; ++r1) {
                const int m = mbase + r1 + 8 * r2;
                const float xs = xsq[m];
                #pragma unroll
                for (int ni = 0; ni < 2; ++ni) {
                    const int n = tile_n + waveCol * 64 + ni * 32 + l32;
                    out[(size_t)m * OUT_DIM + n] =
                        xs + wsq[n] - 2.0f * acc[mi][ni][r2 * 4 + r1];
                }
            }
        }
    }
}

// ---------------------------------------------------------------------------
extern "C" void kernel_launch(void* const* d_in, const int* in_sizes, int n_in,
                              void* d_out, int out_size, void* d_ws, size_t ws_size,
                              hipStream_t stream)
{
    const float* x   = (const float*)d_in[0];   // (8192, 1024) fp32
    const float* wgt = (const float*)d_in[1];   // (1024, 4096) fp32
    float* out = (float*)d_out;                 // (8192, 4096) fp32
    char*  ws  = (char*)d_ws;

    // workspace layout: xb (16 MB) | wT (8 MB) | xsq (32 KB) | wsq (16 KB)
    unsigned short* xb = (unsigned short*)ws;
    unsigned short* wT = (unsigned short*)(ws + (size_t)B_DIM * IN_DIM * 2);
    float* xsq = (float*)(ws + (size_t)B_DIM * IN_DIM * 2 + (size_t)OUT_DIM * IN_DIM * 2);
    float* wsq = xsq + B_DIM;

    convert_x_kernel<<<B_DIM / 4, 256, 0, stream>>>(x, xb, xsq, wsq);
    convert_w_kernel<<<dim3(OUT_DIM / 64, IN_DIM / 64), 256, 0, stream>>>(wgt, wT, wsq);
    rbf_gemm_kernel<<<dim3(B_DIM / 128, OUT_DIM / 128), 256, 0, stream>>>(xb, wT, xsq, wsq, out);
}